// Round 8
// baseline (3585.391 us; speedup 1.0000x reference)
//
#include <hip/hip_runtime.h>
#include <hip/hip_bf16.h>
#include <math.h>

// Problem dims (fixed by the reference)
#define RB 64
#define RS 512
#define RE 1024
#define RH 1024
#define BSH ((size_t)RB * RS * RH)

// scan decomposition: 256 blocks = 64 col-groups x 4 row-groups.
// The 4 row groups are INDEPENDENT scans (disjoint batch rows).
//
// Sync: TAGGED DATA (proven correct on HW in round 7; ws_size >= 512 KB also
// proven there). h3 element -> u32 ((t+1)<<16 | bf16). Dword stores are
// HW-atomic, so tag+payload are inseparable: no producer drain, no flag, no
// barrier, no fences. Consumers poll the data itself: the poll IS the full
// 32-u64 burst + verify — detect and fetch are ONE L3 round trip per round.
// Self-validating reads make any compiler/HW reordering harmless.
//
// Lap safety (ping-pong induction, unchanged): publishing tag t+2 into
// buffer t&1 requires passing the poll for tag t+1, which requires every
// block of the row group to have published t+1 — which each does only AFTER
// its step-t reads of buffer t&1. A consumer polling tag t can thus only see
// tag t (fresh) or t-2/poison (stale, caught by verify) in that buffer.
//
// Round-8 changes vs round 7 (same protocol, implementation fixed):
//  * NO sentinel (it covered 1 of 8 producers -> premature bursts -> retries;
//    FETCH 205->274 MB was the retry re-reads).
//  * __launch_bounds__(256, 1): the scan runs exactly 1 block/CU, so let the
//    compiler keep q[32] (64 VGPR) fully in registers and issue all 32 loads
//    concurrently (round 7's VGPR=80 serialized the burst; VALUBusy 8.4%).
//  * Cheaper verify: XOR + OR-accumulate, single hi16 mask at the end.
#define NBLK 256

typedef __attribute__((ext_vector_type(8))) __bf16 bf16x8;
typedef __attribute__((ext_vector_type(4))) float  f32x4;

__device__ __forceinline__ bf16x8 cvt8(f32x4 a, f32x4 b) {
    bf16x8 r;
    r[0] = (__bf16)a[0]; r[1] = (__bf16)a[1];
    r[2] = (__bf16)a[2]; r[3] = (__bf16)a[3];
    r[4] = (__bf16)b[0]; r[5] = (__bf16)b[1];
    r[6] = (__bf16)b[2]; r[7] = (__bf16)b[3];
    return r;
}

// ---------------------------------------------------------------------------
// Phase 0: poison all tags (0xFFFF > any step) — 2*RB*RH = 131072 u32.
// ---------------------------------------------------------------------------
__global__ __launch_bounds__(256) void init_tags_k(unsigned* tbuf) {
    const int i = blockIdx.x * 256 + threadIdx.x;      // grid 256 -> 65536
    tbuf[i]         = 0xFFFF0000u;
    tbuf[i + 65536] = 0xFFFF0000u;
}

// ---------------------------------------------------------------------------
// Phase 1: wx[m,h] = sum_e x[m,e]*W_w[h,e] + W_b[h]
// 128x128 tile, BK=64, reg-staged fp32->bf16 into padded LDS, 2x2 wave grid,
// 4x4 16x16x32 MFMA fragments per wave. (unchanged — known good)
// ---------------------------------------------------------------------------
#define WBK  64
#define LDST 72   // 64 + 8 pad bf16 elems; 144 B row stride (16B-aligned)

__global__ __launch_bounds__(256) void wx_gemm(
    const float* __restrict__ X,
    const float* __restrict__ Ww,
    const float* __restrict__ Wb,
    float* __restrict__ Out)
{
    __shared__ __align__(16) __bf16 As[128 * LDST];
    __shared__ __align__(16) __bf16 Bs[128 * LDST];

    const int tid  = threadIdx.x;
    const int lane = tid & 63;
    const int wave = tid >> 6;
    const int m0   = blockIdx.y * 128;
    const int n0   = blockIdx.x * 128;
    const int wm   = (wave >> 1) * 64;
    const int wn   = (wave & 1) * 64;

    const int sk   = (tid & 7) * 8;
    const int srow = tid >> 3;

    f32x4 acc[4][4];
#pragma unroll
    for (int i = 0; i < 4; ++i)
#pragma unroll
        for (int j = 0; j < 4; ++j) acc[i][j] = (f32x4){0.f, 0.f, 0.f, 0.f};

    for (int kc = 0; kc < RE; kc += WBK) {
#pragma unroll
        for (int rr = 0; rr < 128; rr += 32) {
            const float* xp = X + (size_t)(m0 + srow + rr) * RE + kc + sk;
            *reinterpret_cast<bf16x8*>(&As[(srow + rr) * LDST + sk]) =
                cvt8(*reinterpret_cast<const f32x4*>(xp),
                     *reinterpret_cast<const f32x4*>(xp + 4));
            const float* wp = Ww + (size_t)(n0 + srow + rr) * RE + kc + sk;
            *reinterpret_cast<bf16x8*>(&Bs[(srow + rr) * LDST + sk]) =
                cvt8(*reinterpret_cast<const f32x4*>(wp),
                     *reinterpret_cast<const f32x4*>(wp + 4));
        }
        __syncthreads();

#pragma unroll
        for (int ks = 0; ks < 2; ++ks) {
            bf16x8 af[4], bfr[4];
#pragma unroll
            for (int i = 0; i < 4; ++i) {
                af[i]  = *reinterpret_cast<const bf16x8*>(
                    &As[(wm + i * 16 + (lane & 15)) * LDST + ks * 32 + (lane >> 4) * 8]);
                bfr[i] = *reinterpret_cast<const bf16x8*>(
                    &Bs[(wn + i * 16 + (lane & 15)) * LDST + ks * 32 + (lane >> 4) * 8]);
            }
#pragma unroll
            for (int i = 0; i < 4; ++i)
#pragma unroll
                for (int j = 0; j < 4; ++j)
                    acc[i][j] = __builtin_amdgcn_mfma_f32_16x16x32_bf16(
                        af[i], bfr[j], acc[i][j], 0, 0, 0);
        }
        __syncthreads();
    }

    const int col = lane & 15, rbase = (lane >> 4) * 4;
#pragma unroll
    for (int j = 0; j < 4; ++j) {
        const int n = n0 + wn + j * 16 + col;
        const float bias = Wb[n];
#pragma unroll
        for (int i = 0; i < 4; ++i) {
#pragma unroll
            for (int r = 0; r < 4; ++r) {
                const int m = m0 + wm + i * 16 + rbase + r;
                Out[(size_t)m * RH + n] = acc[i][j][r] + bias;
            }
        }
    }
}

// ---------------------------------------------------------------------------
// Phase 2: persistent scan, barrier-free tagged-data exchange.
// 256 blocks x 256 thr (4 waves, K=256 each, ufr[8]). Block (cg,rg) owns the
// 16x16 patch rows [16rg,+16) x cols [16cg,+16). Per-step sync = full-burst
// poll (32 u64/lane, all in flight) + verify. One __syncthreads per step
// (parity-buffered LDS reduce). Runs exactly 1 block/CU -> launch_bounds
// min-waves=1 so the burst stays register-resident.
// ---------------------------------------------------------------------------
__global__ __launch_bounds__(256, 1) void rnn_scan_tag(
    const float* __restrict__ Uw,
    const float* __restrict__ Ub,
    float* Out,               // [B*S*H] (wx -> result1) then [B*H] t_final
    unsigned* tbuf)           // 2 * B * H tagged u32 h3, double-buffered
{
    __shared__ float red[2][4 * 256];
    __shared__ float ubs[16];

    const int tid  = threadIdx.x;
    const int lane = tid & 63;
    const int wave = tid >> 6;           // K-slice index 0..3
    const int bid  = blockIdx.x;
    const int cg   = bid >> 2;           // column group 0..63
    const int rg   = bid & 3;            // row group 0..3 (independent scan)
    const int col0 = cg * 16;
    const int row0 = rg * 16;

    // register-resident U^T slice: n = lane&15, k = 256*wave + 32*j + (lane>>4)*8
    bf16x8 ufr[8];
    {
        const float* up = Uw + (size_t)(col0 + (lane & 15)) * RH
                        + 256 * wave + ((lane >> 4) * 8);
#pragma unroll
        for (int j = 0; j < 8; ++j)
            ufr[j] = cvt8(*reinterpret_cast<const f32x4*>(up + j * 32),
                          *reinterpret_cast<const f32x4*>(up + j * 32 + 4));
    }
    if (tid < 16) ubs[tid] = Ub[col0 + tid];

    // epilogue mapping: thread -> one element of the 16x16 patch
    const int erow = row0 + (tid >> 4);
    const int ecol = col0 + (tid & 15);

    // --- h3_0 = tanh(wx[:, 0, patch]), published with tag 0 (hi16 = 0) ---
    {
        const float w = Out[(size_t)erow * RS * RH + ecol];
        union { __bf16 b; unsigned short s; } u; u.b = (__bf16)tanhf(w);
        __hip_atomic_store(&tbuf[(size_t)erow * RH + ecol], (unsigned)u.s,
                           __ATOMIC_RELAXED, __HIP_MEMORY_SCOPE_AGENT);
    }
    // wx prefetch: wn_cur = wx(t+1) for the tanh in step t's epilogue
    float wn_cur = Out[(size_t)erow * RS * RH + (size_t)1 * RH + ecol];

    const int arow  = row0 + (lane & 15);          // batch row for A-frags
    const int kbase = 256 * wave + (lane >> 4) * 8;

    for (int t = 0; t < RS; ++t) {
        const unsigned* cur = tbuf + (size_t)(t & 1) * (RB * RH);
        unsigned*       nxt = tbuf + (size_t)((t + 1) & 1) * (RB * RH);
        // u64 view of this lane's tagged A-frag row (frag f at +f*16 u64)
        const unsigned long long* cp =
            reinterpret_cast<const unsigned long long*>(cur)
            + ((size_t)arow * RH + kbase) / 2;

        const unsigned long long half = ((unsigned long long)(unsigned)t) << 16;
        const unsigned long long rep  = half | (half << 32);
        const unsigned long long hm   = 0xFFFF0000FFFF0000ull;

        // --- poll = full burst + verify. All 32 loads issued per round
        // (one L3 round trip); retry until every tag in every lane == t.
        unsigned long long q[32];
        while (true) {
#pragma unroll
            for (int j = 0; j < 32; ++j)
                q[j] = __hip_atomic_load(cp + (size_t)(j >> 2) * 16 + (j & 3),
                                         __ATOMIC_RELAXED,
                                         __HIP_MEMORY_SCOPE_AGENT);
            unsigned long long bad = 0;
#pragma unroll
            for (int j = 0; j < 32; ++j) { q[j] ^= rep; bad |= q[j]; }
            if (__all((bad & hm) == 0ull)) break;
            __builtin_amdgcn_s_sleep(1);
        }

        // --- pack the (hi16-clean) payloads into bf16x8 MFMA A-frags ---
        bf16x8 xf[8];
#pragma unroll
        for (int f = 0; f < 8; ++f) {
            union { unsigned u[4]; bf16x8 v; } w;
#pragma unroll
            for (int i = 0; i < 4; ++i) {
                const unsigned long long y = q[f * 4 + i];
                const unsigned lo = (unsigned)y;            // col 2i   | 0 hi16
                const unsigned hi = (unsigned)(y >> 32);    // col 2i+1 | 0 hi16
                w.u[i] = lo | (hi << 16);
            }
            xf[f] = w.v;
        }

        f32x4 ac0 = (f32x4){0.f, 0.f, 0.f, 0.f};
        f32x4 ac1 = ac0, ac2 = ac0, ac3 = ac0;
        ac0 = __builtin_amdgcn_mfma_f32_16x16x32_bf16(xf[0], ufr[0], ac0, 0, 0, 0);
        ac1 = __builtin_amdgcn_mfma_f32_16x16x32_bf16(xf[1], ufr[1], ac1, 0, 0, 0);
        ac2 = __builtin_amdgcn_mfma_f32_16x16x32_bf16(xf[2], ufr[2], ac2, 0, 0, 0);
        ac3 = __builtin_amdgcn_mfma_f32_16x16x32_bf16(xf[3], ufr[3], ac3, 0, 0, 0);
        ac0 = __builtin_amdgcn_mfma_f32_16x16x32_bf16(xf[4], ufr[4], ac0, 0, 0, 0);
        ac1 = __builtin_amdgcn_mfma_f32_16x16x32_bf16(xf[5], ufr[5], ac1, 0, 0, 0);
        ac2 = __builtin_amdgcn_mfma_f32_16x16x32_bf16(xf[6], ufr[6], ac2, 0, 0, 0);
        ac3 = __builtin_amdgcn_mfma_f32_16x16x32_bf16(xf[7], ufr[7], ac3, 0, 0, 0);
        const f32x4 acc = (ac0 + ac1) + (ac2 + ac3);

        // --- cross-wave K reduction, parity-buffered: ONE barrier per step ---
        float* rb = red[t & 1];
#pragma unroll
        for (int r = 0; r < 4; ++r)
            rb[wave * 256 + ((lane >> 4) * 4 + r) * 16 + (lane & 15)] = acc[r];
        __syncthreads();

        const float v = rb[tid] + rb[256 + tid] + rb[512 + tid] + rb[768 + tid]
                      + ubs[tid & 15];
        const size_t oidx = (size_t)erow * RS * RH + (size_t)t * RH + ecol;
        if (t == RS - 1) {
            Out[oidx] = v;
            Out[BSH + (size_t)erow * RH + ecol] = v;    // t_final
        } else {
            // publish FIRST (peers' critical path), then local HBM stores
            const float h = tanhf(wn_cur + v);
            union { __bf16 b; unsigned short s; } u; u.b = (__bf16)h;
            const unsigned tv = ((unsigned)(t + 1) << 16) | (unsigned)u.s;
            __hip_atomic_store(&nxt[(size_t)erow * RH + ecol], tv,
                               __ATOMIC_RELAXED, __HIP_MEMORY_SCOPE_AGENT);
            Out[oidx] = v;
            if (t < RS - 2)
                wn_cur = Out[(size_t)erow * RS * RH + (size_t)(t + 2) * RH + ecol];
        }
    }
}

// ---------------------------------------------------------------------------
extern "C" void kernel_launch(void* const* d_in, const int* in_sizes, int n_in,
                              void* d_out, int out_size, void* d_ws, size_t ws_size,
                              hipStream_t stream)
{
    const float* X  = (const float*)d_in[0];   // [B,S,E] fp32
    const float* Ww = (const float*)d_in[1];   // [H,E]   fp32
    const float* Wb = (const float*)d_in[2];   // [H]     fp32
    const float* Uw = (const float*)d_in[3];   // [H,H]   fp32
    const float* Ub = (const float*)d_in[4];   // [H]     fp32
    float* Out = (float*)d_out;                // [B*S*H] result1 + [B*H] t_final

    unsigned* tbuf = (unsigned*)d_ws;          // 2*B*H tagged u32 = 512 KB

    hipLaunchKernelGGL(init_tags_k, dim3(256), dim3(256), 0, stream, tbuf);
    hipLaunchKernelGGL(wx_gemm, dim3(RH / 128, (RB * RS) / 128), dim3(256), 0, stream,
                       X, Ww, Wb, Out);
    hipLaunchKernelGGL(rnn_scan_tag, dim3(NBLK), dim3(256), 0, stream,
                       Uw, Ub, Out, tbuf);
}